// Round 12
// baseline (852.350 us; speedup 1.0000x reference)
//
#include <hip/hip_runtime.h>
#include <hip/hip_bf16.h>
#include <math.h>

#define B_    8
#define LP_   1024
#define CIN_  64
#define DM_   1024
#define DI_   2048
#define NS_   16
#define PH_   64
#define NH_   32
#define NL_   4
#define GG_   8
#define KH_   2048
#define DIN_  4160
#define CONVD_ 2080
#define L_    128
#define R_    1024
#define OUTL_ 512
#define COUT_ 64

typedef __bf16 bf16x8 __attribute__((ext_vector_type(8)));
typedef float f32x4 __attribute__((ext_vector_type(4)));
typedef unsigned short ushort;

__device__ __forceinline__ float silu_f(float x) { return x / (1.0f + expf(-x)); }

__device__ __forceinline__ ushort f2bu(float x) {
    union { __hip_bfloat16 h; ushort u; } c; c.h = __float2bfloat16(x); return c.u;
}
__device__ __forceinline__ float bu2f(ushort u) {
    union { ushort u; __hip_bfloat16 h; } c; c.u = u; return __bfloat162float(c.h);
}

__device__ __forceinline__ void gload_lds16(const void* g, void* l) {
    __builtin_amdgcn_global_load_lds((const __attribute__((address_space(1))) unsigned int*)g,
                                     (__attribute__((address_space(3))) unsigned int*)l, 16, 0, 0);
}

// pair-merge reduce: 8 accumulators x 64 lanes -> lane (l&7) holds full sum of acc[l&7]
__device__ __forceinline__ float merge2(float a, float b, int mask, int lane) {
    float x = (lane & mask) ? b : a;
    float y = (lane & mask) ? a : b;
    return x + __shfl_xor(y, mask);
}
__device__ __forceinline__ float reduce8(float* a, int lane) {
    float c0 = merge2(a[0], a[1], 1, lane);
    float c1 = merge2(a[2], a[3], 1, lane);
    float c2 = merge2(a[4], a[5], 1, lane);
    float c3 = merge2(a[6], a[7], 1, lane);
    float d0 = merge2(c0, c1, 2, lane);
    float d1 = merge2(c2, c3, 2, lane);
    float e  = merge2(d0, d1, 4, lane);
    e += __shfl_xor(e, 8);
    e += __shfl_xor(e, 16);
    e += __shfl_xor(e, 32);
    return e;
}

// ---------------- prep: pre/patch weight transposes + im2col (bf16 out) ----------------
#define PREP_W1 327680       // DM_*320
#define PREP_W2 8388608      // DM_*8192
#define PREP_W3 2621440      // 8192*320
#define PREP_TOT 11337728
__global__ __launch_bounds__(256) void k_prep(
    const float* __restrict__ pre_w, const float* __restrict__ patch_w, const float* __restrict__ xp,
    __hip_bfloat16* __restrict__ wpreT, __hip_bfloat16* __restrict__ wpatchT, __hip_bfloat16* __restrict__ Apre)
{
    int idx = blockIdx.x * 256 + threadIdx.x;
    if (idx < PREP_W1) {
        int d = idx / 320, kk = idx % 320;
        int kp = kk >> 6, c = kk & 63;
        wpreT[idx] = __float2bfloat16(pre_w[(d * CIN_ + c) * 5 + kp]);
    } else if (idx < PREP_W1 + PREP_W2) {
        int i = idx - PREP_W1;
        int d = i >> 13, kk = i & 8191;
        int kp = kk >> 10, din = kk & 1023;
        wpatchT[i] = __float2bfloat16(patch_w[((size_t)d << 13) + din * 8 + kp]);
    } else if (idx < PREP_TOT) {
        int i = idx - PREP_W1 - PREP_W2;
        int kk = i % 320; int r = i / 320;
        int l = r & 1023, b = r >> 10;
        int kp = kk >> 6, c = kk & 63;
        int lp = l + kp - 2;
        float v = 0.f;
        if (lp >= 0 && lp < LP_) v = xp[((size_t)b * LP_ + lp) * CIN_ + c];
        Apre[i] = __float2bfloat16(v);
    }
}

// ---------------- bf16 MFMA GEMM, 128^2 tile, 8 waves, BK=32, dbuf, granule swizzle,
// T1 XCD-aware block swizzle. BF32=1: B consumed directly as fp32 (Bf0/Bf1 per dir),
// reg-staged + converted + ds_written AFTER the MFMAs (T14 split: HBM latency hides
// under compute; T1 makes the 8 per-panel re-reads L2-local).
template<int BM, int BN, int BF32>
__global__ __launch_bounds__(512) void k_gemm_mfma(
    const ushort* __restrict__ A, const ushort* __restrict__ Bb,
    const float* __restrict__ Bf0, const float* __restrict__ Bf1,
    const float* __restrict__ bias,
    float* __restrict__ Cf, __hip_bfloat16* __restrict__ Cb,
    int Kc, int ldkA, int ldkB, int ldc, int Nstore, int act, int nsplit, int Nb,
    long sA, long sC)
{
    constexpr int BK = 32;
    constexpr int WM = 64, WN = 32;           // 2x4 waves cover 128x128
    constexpr int MR = WM / 16, NR = WN / 16; // 4 x 2
    __shared__ ushort sAs[2][BM * BK];
    __shared__ ushort sBs[2][BN * BK];
    int tid = threadIdx.x;
    int lane = tid & 63, w = tid >> 6;        // 8 waves
    int wr = w >> 2, wc = w & 3;
    int z = blockIdx.z;
    int dir = z / nsplit, ks = z - dir * nsplit;
    int kbase = ks * Kc;
    // T1 bijective XCD remap (nwg%8==0 for all our grids): each XCD gets a contiguous
    // bx-range (all by) -> B panels resident in ONE per-XCD L2.
    int H = blockIdx.y * gridDim.x + blockIdx.x;
    int nwg = gridDim.x * gridDim.y;
    int chunk = nwg >> 3;
    int Lid = (H & 7) * chunk + (H >> 3);
    int bx = Lid / gridDim.y;
    int by = Lid - bx * gridDim.y;
    int m0 = by * BM, n0 = bx * BN;
    const ushort* Az = A + (size_t)dir * sA + kbase;
    const ushort* Bz = BF32 ? nullptr : (Bb + kbase);            // bf16 path: dir==0 users only
    const float*  Bfz = BF32 ? ((dir ? Bf1 : Bf0) + kbase) : nullptr;

    // per-thread staging coordinates (ACH = BM*4 = 512 = blockDim: one 16B chunk each)
    const int srow = tid >> 2, sgp = tid & 3;
    const int sg = sgp ^ ((srow >> 1) & 3);   // swizzled source granule
    const bool brow_ok = BF32 ? (n0 + srow < Nb) : true;

    auto STAGE_A = [&](int buf, int k0) {
        gload_lds16(Az + (size_t)(m0 + srow) * ldkA + k0 + sg * 8, (char*)&sAs[buf][0] + tid * 16);
    };
    auto STAGE_B16 = [&](int buf, int k0) {
        gload_lds16(Bz + (size_t)(n0 + srow) * ldkB + k0 + sg * 8, (char*)&sBs[buf][0] + tid * 16);
    };
    float4 nb0 = {0,0,0,0}, nb1 = {0,0,0,0};
    auto LOAD_B32 = [&](int k0) {
        if (brow_ok) {
            const float* p = Bfz + (size_t)(n0 + srow) * ldkB + k0 + sg * 8;
            nb0 = *(const float4*)p;
            nb1 = *(const float4*)(p + 4);
        } else { nb0 = {0,0,0,0}; nb1 = {0,0,0,0}; }
    };
    auto WRITE_B32 = [&](int buf) {
        ushort4 p0, p1;
        p0.x = f2bu(nb0.x); p0.y = f2bu(nb0.y); p0.z = f2bu(nb0.z); p0.w = f2bu(nb0.w);
        p1.x = f2bu(nb1.x); p1.y = f2bu(nb1.y); p1.z = f2bu(nb1.z); p1.w = f2bu(nb1.w);
        ushort* dst = (ushort*)((char*)&sBs[buf][0] + tid * 16);
        *(ushort4*)dst = p0;
        *(ushort4*)(dst + 4) = p1;
    };

    // swizzled fragment granule (elements)
    const int gsw = (((lane >> 4) ^ ((lane >> 1) & 3)) * 8);

    f32x4 acc[MR][NR] = {};
    const int NT = Kc / BK;
    STAGE_A(0, 0);
    if (BF32) { LOAD_B32(0); WRITE_B32(0); }
    else      STAGE_B16(0, 0);
    __syncthreads();
    int cur = 0;
    for (int t = 0; t < NT; ++t) {
        bool pref = (t + 1 < NT);
        if (pref) {
            STAGE_A(cur ^ 1, (t + 1) * BK);             // async, in flight during compute
            if (BF32) LOAD_B32((t + 1) * BK);           // reg loads, waited after MFMA
            else      STAGE_B16(cur ^ 1, (t + 1) * BK);
        }
        bf16x8 af[MR], bfr[NR];
        #pragma unroll
        for (int m = 0; m < MR; ++m)
            af[m] = *(const bf16x8*)&sAs[cur][(wr * WM + m * 16 + (lane & 15)) * BK + gsw];
        #pragma unroll
        for (int n = 0; n < NR; ++n)
            bfr[n] = *(const bf16x8*)&sBs[cur][(wc * WN + n * 16 + (lane & 15)) * BK + gsw];
        #pragma unroll
        for (int m = 0; m < MR; ++m)
            #pragma unroll
            for (int n = 0; n < NR; ++n)
                acc[m][n] = __builtin_amdgcn_mfma_f32_16x16x32_bf16(af[m], bfr[n], acc[m][n], 0, 0, 0);
        if (BF32 && pref) WRITE_B32(cur ^ 1);           // convert+write after MFMAs (latency hidden)
        __syncthreads();                                 // drains vmcnt + lgkmcnt
        cur ^= 1;
    }
    #pragma unroll
    for (int m = 0; m < MR; ++m) {
        int row = m0 + wr * WM + m * 16 + (lane >> 4) * 4;
        #pragma unroll
        for (int n = 0; n < NR; ++n) {
            int col = n0 + wc * WN + n * 16 + (lane & 15);
            if (col < Nstore) {
                if (act == 2) {
                    float* Cfz = Cf + (size_t)z * sC;
                    #pragma unroll
                    for (int j = 0; j < 4; ++j)
                        Cfz[(size_t)(row + j) * ldc + col] = acc[m][n][j];
                } else {
                    __hip_bfloat16* Cbz = Cb + (size_t)dir * sC;
                    float bv = bias ? bias[col] : 0.f;
                    #pragma unroll
                    for (int j = 0; j < 4; ++j) {
                        float v = acc[m][n][j] + bv;
                        if (act == 1) v = silu_f(v);
                        Cbz[(size_t)(row + j) * ldc + col] = __float2bfloat16(v);
                    }
                }
            }
        }
    }
}

// ---------------- patch finalize + first rmsnorm: one block per hf row ----------------
__global__ __launch_bounds__(256) void k_patch_fin_rms(const float* __restrict__ part, const float* __restrict__ bias,
                                                       const float* __restrict__ w0, const float* __restrict__ w1,
                                                       float* __restrict__ hf, float* __restrict__ hb,
                                                       __hip_bfloat16* __restrict__ uB) {
    int r = blockIdx.x;          // 0..1023
    int t = threadIdx.x;
    int c = t * 4;
    float4 o = *(const float4*)(bias + c);
    #pragma unroll
    for (int s = 0; s < 8; ++s) {
        float4 v = *(const float4*)(part + (size_t)s * 1048576 + ((size_t)r << 10) + c);
        o.x += v.x; o.y += v.y; o.z += v.z; o.w += v.w;
    }
    *(float4*)(hf + ((size_t)r << 10) + c) = o;
    int rb = r ^ 127;
    *(float4*)(hb + ((size_t)rb << 10) + c) = o;
    float ss = o.x * o.x + o.y * o.y + o.z * o.z + o.w * o.w;
    #pragma unroll
    for (int of = 32; of; of >>= 1) ss += __shfl_xor(ss, of);
    __shared__ float sred[4];
    if ((t & 63) == 0) sred[t >> 6] = ss;
    __syncthreads();
    float tot = sred[0] + sred[1] + sred[2] + sred[3];
    float scale = rsqrtf(tot * (1.0f / DM_) + 1e-5f);
    float4 wf = *(const float4*)(w0 + c);
    float4 wb = *(const float4*)(w1 + c);
    __hip_bfloat16* uf = uB + ((size_t)r << 10) + c;
    __hip_bfloat16* ub = uB + ((size_t)(1024 + rb) << 10) + c;
    uf[0] = __float2bfloat16(o.x * scale * wf.x); uf[1] = __float2bfloat16(o.y * scale * wf.y);
    uf[2] = __float2bfloat16(o.z * scale * wf.z); uf[3] = __float2bfloat16(o.w * scale * wf.w);
    ub[0] = __float2bfloat16(o.x * scale * wb.x); ub[1] = __float2bfloat16(o.y * scale * wb.y);
    ub[2] = __float2bfloat16(o.z * scale * wb.z); ub[3] = __float2bfloat16(o.w * scale * wb.w);
}

// ---------------- out-proj finalize (+residual) + next rmsnorm: one block per h row (2048) ----------------
template<bool DO_RMS>
__global__ __launch_bounds__(256) void k_oproj_fin_rms(const float* __restrict__ part,
                                                       const float* __restrict__ w0, const float* __restrict__ w1,
                                                       float* __restrict__ h, __hip_bfloat16* __restrict__ uB) {
    int row = blockIdx.x;        // 0..2047 (dir = row>>10)
    int t = threadIdx.x;
    int c = t * 4;
    const float* p = part + (size_t)(row >> 10) * 4194304 + (size_t)(row & 1023) * 1024 + c;
    float4 o = *(const float4*)(h + ((size_t)row << 10) + c);
    #pragma unroll
    for (int s = 0; s < 4; ++s) {
        float4 v = *(const float4*)(p + (size_t)s * 1048576);
        o.x += v.x; o.y += v.y; o.z += v.z; o.w += v.w;
    }
    *(float4*)(h + ((size_t)row << 10) + c) = o;
    if (DO_RMS) {
        float ss = o.x * o.x + o.y * o.y + o.z * o.z + o.w * o.w;
        #pragma unroll
        for (int of = 32; of; of >>= 1) ss += __shfl_xor(ss, of);
        __shared__ float sred[4];
        if ((t & 63) == 0) sred[t >> 6] = ss;
        __syncthreads();
        float tot = sred[0] + sred[1] + sred[2] + sred[3];
        float scale = rsqrtf(tot * (1.0f / DM_) + 1e-5f);
        const float* w = (row >> 10) ? w1 : w0;
        float4 wv = *(const float4*)(w + c);
        __hip_bfloat16* u = uB + ((size_t)row << 10) + c;
        u[0] = __float2bfloat16(o.x * scale * wv.x); u[1] = __float2bfloat16(o.y * scale * wv.y);
        u[2] = __float2bfloat16(o.z * scale * wv.z); u[3] = __float2bfloat16(o.w * scale * wv.w);
    }
}

// ---------------- SSM scan with fused depthwise conv: one block per (dir,b,h) ----------------
__global__ __launch_bounds__(256) void k_scan(const __hip_bfloat16* __restrict__ zx,
                                              const float* __restrict__ cw0, const float* __restrict__ cw1,
                                              const float* __restrict__ cb0, const float* __restrict__ cb1,
                                              const float* __restrict__ dtb0, const float* __restrict__ dtb1,
                                              const float* __restrict__ al0, const float* __restrict__ al1,
                                              const float* __restrict__ D0, const float* __restrict__ D1,
                                              __hip_bfloat16* __restrict__ ys) {
    __shared__ float xs[L_ * PH_];
    __shared__ float Bsh[L_ * NS_];
    __shared__ float Csh[L_ * NS_];
    __shared__ float dts[L_];
    __shared__ float dAs[L_];
    int bx = blockIdx.x;
    int dir = bx >> 8, b = (bx >> 5) & 7, h = bx & 31;
    const __hip_bfloat16* zxd = zx + (size_t)dir * 1024 * DIN_;
    const float* cw = dir ? cw1 : cw0;
    const float* cb = dir ? cb1 : cb0;
    const float* dt_bias = dir ? dtb1 : dtb0;
    const float* A_log   = dir ? al1 : al0;
    const float* Dh      = dir ? D1 : D0;
    __hip_bfloat16* ysd  = ys + (size_t)dir * 1024 * DI_;
    int t = threadIdx.x;
    for (int i = t; i < 2048; i += 256) {
        int l = i >> 4, p4 = i & 15;
        int cc = h * PH_ + p4 * 4;
        float a0 = cb[cc + 0], a1 = cb[cc + 1], a2 = cb[cc + 2], a3 = cb[cc + 3];
        #pragma unroll
        for (int k = 0; k < 4; ++k) {
            int lp = l - 3 + k;
            if (lp >= 0) {
                ushort4 raw = *(const ushort4*)(zxd + (size_t)(b * L_ + lp) * DIN_ + DI_ + cc);
                a0 += bu2f(raw.x) * cw[(cc + 0) * 4 + k];
                a1 += bu2f(raw.y) * cw[(cc + 1) * 4 + k];
                a2 += bu2f(raw.z) * cw[(cc + 2) * 4 + k];
                a3 += bu2f(raw.w) * cw[(cc + 3) * 4 + k];
            }
        }
        float* xp = &xs[l * PH_ + p4 * 4];
        xp[0] = silu_f(a0); xp[1] = silu_f(a1); xp[2] = silu_f(a2); xp[3] = silu_f(a3);
    }
    for (int i = t; i < 1024; i += 256) {
        int l = i >> 3, q4 = i & 7;
        int cc = DI_ + q4 * 4;
        float a0 = cb[cc + 0], a1 = cb[cc + 1], a2 = cb[cc + 2], a3 = cb[cc + 3];
        #pragma unroll
        for (int k = 0; k < 4; ++k) {
            int lp = l - 3 + k;
            if (lp >= 0) {
                ushort4 raw = *(const ushort4*)(zxd + (size_t)(b * L_ + lp) * DIN_ + DI_ + cc);
                a0 += bu2f(raw.x) * cw[(cc + 0) * 4 + k];
                a1 += bu2f(raw.y) * cw[(cc + 1) * 4 + k];
                a2 += bu2f(raw.z) * cw[(cc + 2) * 4 + k];
                a3 += bu2f(raw.w) * cw[(cc + 3) * 4 + k];
            }
        }
        float r0 = silu_f(a0), r1 = silu_f(a1), r2 = silu_f(a2), r3 = silu_f(a3);
        if (q4 < 4) {
            float* bp = &Bsh[l * NS_ + q4 * 4];
            bp[0] = r0; bp[1] = r1; bp[2] = r2; bp[3] = r3;
        } else {
            float* cp = &Csh[l * NS_ + (q4 - 4) * 4];
            cp[0] = r0; cp[1] = r1; cp[2] = r2; cp[3] = r3;
        }
    }
    if (t < L_) {
        float v = bu2f(*(const ushort*)(zxd + (size_t)(b * L_ + t) * DIN_ + 4128 + h)) + dt_bias[h];
        float sp = v > 20.f ? v : log1pf(expf(v));
        dts[t] = sp;
        dAs[t] = expf(-expf(A_log[h]) * sp);
    }
    __syncthreads();
    int p = t >> 2, n0 = (t & 3) * 4;
    float Dv = Dh[h];
    float s0 = 0.f, s1 = 0.f, s2 = 0.f, s3 = 0.f;
    for (int l = 0; l < L_; ++l) {
        float x = xs[l * 64 + p];
        float dAv = dAs[l];
        float xdt = x * dts[l];
        s0 = s0 * dAv + xdt * Bsh[l * 16 + n0 + 0];
        s1 = s1 * dAv + xdt * Bsh[l * 16 + n0 + 1];
        s2 = s2 * dAv + xdt * Bsh[l * 16 + n0 + 2];
        s3 = s3 * dAv + xdt * Bsh[l * 16 + n0 + 3];
        float cp = s0 * Csh[l * 16 + n0 + 0] + s1 * Csh[l * 16 + n0 + 1]
                 + s2 * Csh[l * 16 + n0 + 2] + s3 * Csh[l * 16 + n0 + 3];
        cp += __shfl_xor(cp, 1);
        cp += __shfl_xor(cp, 2);
        if ((t & 3) == 0) xs[l * 64 + p] = cp + x * Dv;
    }
    __syncthreads();
    for (int i = t; i < L_ * PH_; i += 256) {
        int l = i >> 6, pp = i & 63;
        float z = bu2f(*(const ushort*)(zxd + (size_t)(b * L_ + l) * DIN_ + h * PH_ + pp));
        ysd[((size_t)(b * L_ + l)) * DI_ + h * PH_ + pp] = __float2bfloat16(xs[i] * silu_f(z));
    }
}

// ---------------- tail: meanctx + aux + KAN1 basis, one dispatch ----------------
__device__ __forceinline__ void emit_basis(float v, float lbw, float* __restrict__ bas, size_t base) {
    float bw = expf(lbw) + 1e-6f;
    float inv = 1.0f / (2.0f * bw * bw);
    #pragma unroll
    for (int g = 0; g < GG_; ++g) {
        float gg = -2.0f + g * (4.0f / 7.0f);
        float df = v - gg;
        bas[base + g] = expf(-df * df * inv);
    }
}

__global__ __launch_bounds__(256) void k_meanctx_aux(const float* __restrict__ hf, const float* __restrict__ hb,
                                                     const float* __restrict__ y_aux, const float* __restrict__ aux_w,
                                                     const float* __restrict__ aux_b, const float* __restrict__ k1_lbw,
                                                     float* __restrict__ fused, float* __restrict__ bas1) {
    int bx = blockIdx.x;
    int t = threadIdx.x;
    if (bx < 64) {
        int b = bx >> 3, ch = bx & 7;
        int d4 = t & 31, lg = t >> 5;
        int d = ch * 128 + d4 * 4;
        float4 sf = {0,0,0,0}, sb = {0,0,0,0};
        for (int l = lg; l < L_; l += 8) {
            float4 a = *(const float4*)(hf + ((size_t)b * L_ + l) * DM_ + d);
            float4 c = *(const float4*)(hb + ((size_t)b * L_ + l) * DM_ + d);
            sf.x += a.x; sf.y += a.y; sf.z += a.z; sf.w += a.w;
            sb.x += c.x; sb.y += c.y; sb.z += c.z; sb.w += c.w;
        }
        __shared__ float rf[8][128], rb[8][128];
        *(float4*)&rf[lg][d4 * 4] = sf;
        *(float4*)&rb[lg][d4 * 4] = sb;
        __syncthreads();
        if (t < 128) {
            float s1 = 0.f, s2 = 0.f;
            #pragma unroll
            for (int g = 0; g < 8; ++g) { s1 += rf[g][t]; s2 += rb[g][t]; }
            s1 *= (1.f / L_); s2 *= (1.f / L_);
            int d1 = ch * 128 + t, d2 = DM_ + ch * 128 + t;
            fused[b * 3072 + d1] = s1;
            fused[b * 3072 + d2] = s2;
            emit_basis(s1, k1_lbw[d1], bas1, ((size_t)b * 3072 + d1) * GG_);
            emit_basis(s2, k1_lbw[d2], bas1, ((size_t)b * 3072 + d2) * GG_);
        }
    } else {
        int j = (bx - 64) * 256 + t;
        if (j >= DM_) return;
        for (int b = 0; b < B_; ++b) {
            float acc = aux_b[j];
            for (int a = 0; a < 32; ++a) acc += y_aux[b * 32 + a] * aux_w[j * 32 + a];
            float v = silu_f(acc);
            int d3 = 2 * DM_ + j;
            fused[b * 3072 + d3] = v;
            emit_basis(v, k1_lbw[d3], bas1, ((size_t)b * 3072 + d3) * GG_);
        }
    }
}

// ---------------- LDS-staged batched dot; y-chunks cover spline (ch<nsp) and base (ch>=nsp) ----------------
template<int MODE>
__global__ __launch_bounds__(256) void k_dotk(const float* __restrict__ Wsp, const float* __restrict__ Xsp, int Ksp,
                                              const float* __restrict__ Wb, const float* __restrict__ Xb, int Kb,
                                              const float* __restrict__ bias, float* __restrict__ out,
                                              int nsp, int nch, int Dout) {
    __shared__ float sX[8][1024];
    int ch = blockIdx.y;
    bool sp = (ch < nsp);
    const float* W = sp ? Wsp : Wb;
    const float* X = sp ? Xsp : Xb;
    int K = sp ? Ksp : Kb;
    int k0 = (sp ? ch : ch - nsp) * 1024;
    int tid = threadIdx.x;
    for (int i = tid; i < 2048; i += 256) {
        int b = i >> 8, kk = (i & 255) * 4;
        *(float4*)&sX[b][kk] = *(const float4*)(X + (size_t)b * K + k0 + kk);
    }
    __syncthreads();
    int wv = tid >> 6, lane = tid & 63;
    int rowBase = blockIdx.x * 32 + wv * 8;
    for (int j = 0; j < 8; ++j) {
        int row = rowBase + j;
        const float* wr = W + (size_t)row * K + k0;
        float acc[8] = {};
        #pragma unroll
        for (int it = 0; it < 4; ++it) {
            int k = it * 256 + lane * 4;
            float4 wvv = *(const float4*)(wr + k);
            #pragma unroll
            for (int b = 0; b < 8; ++b) {
                float4 xv = *(const float4*)&sX[b][k];
                acc[b] += wvv.x * xv.x + wvv.y * xv.y + wvv.z * xv.z + wvv.w * xv.w;
            }
        }
        float e = reduce8(acc, lane);
        if (lane < 8) {
            if (MODE == 0) {
                out[((size_t)row * nch + ch) * 8 + lane] = e;
            } else if (MODE == 1) {
                out[(size_t)lane * Dout + row] = silu_f(e + bias[row]);
            } else {
                int c = row >> 9, l = row & 511;
                out[((size_t)lane * OUTL_ + l) * COUT_ + c] = e + bias[row];
            }
        }
    }
}

// ---------------- KAN1 finalize + basis2 fused ----------------
__global__ __launch_bounds__(256) void k_fin1_basis2(const float* __restrict__ partial, const float* __restrict__ bb,
                                                     const float* __restrict__ k2_lbw,
                                                     float* __restrict__ k1, float* __restrict__ bas2) {
    int row = blockIdx.x * 256 + threadIdx.x;   // 0..2047
    if (row >= 2048) return;
    float bbv = bb[row];
    float lb = expf(k2_lbw[row]) + 1e-6f;
    float inv = 1.0f / (2.0f * lb * lb);
    #pragma unroll
    for (int b = 0; b < 8; ++b) {
        float s = bbv;
        #pragma unroll
        for (int c = 0; c < 27; ++c) s += partial[((size_t)row * 27 + c) * 8 + b];
        float v = silu_f(s);
        k1[(size_t)b * 2048 + row] = v;
        #pragma unroll
        for (int g = 0; g < GG_; ++g) {
            float gg = -2.0f + g * (4.0f / 7.0f);
            float df = v - gg;
            bas2[((size_t)b * 2048 + row) * GG_ + g] = expf(-df * df * inv);
        }
    }
}

template<int NCH>
__global__ __launch_bounds__(256) void k_dot_fin(const float* __restrict__ partial, const float* __restrict__ base_b,
                                                 float* __restrict__ out, int Dout) {
    int row = blockIdx.x * 256 + threadIdx.x;
    if (row >= Dout) return;
    float bb = base_b[row];
    #pragma unroll
    for (int b = 0; b < 8; ++b) {
        float s = bb;
        #pragma unroll
        for (int c = 0; c < NCH; ++c) s += partial[((size_t)row * NCH + c) * 8 + b];
        out[(size_t)b * Dout + row] = silu_f(s);
    }
}

// ---------------- launch ----------------
extern "C" void kernel_launch(void* const* d_in, const int* in_sizes, int n_in,
                              void* d_out, int out_size, void* d_ws, size_t ws_size,
                              hipStream_t stream) {
    const float* x_prefix = (const float*)d_in[0];
    const float* y_aux    = (const float*)d_in[1];
    const float* pre_w    = (const float*)d_in[2];
    const float* pre_b    = (const float*)d_in[3];
    const float* patch_w  = (const float*)d_in[4];
    const float* patch_b  = (const float*)d_in[5];
    const float* norm_w[2] = {(const float*)d_in[6],  (const float*)d_in[14]};
    const float* in_w[2]   = {(const float*)d_in[7],  (const float*)d_in[15]};
    const float* conv_w[2] = {(const float*)d_in[8],  (const float*)d_in[16]};
    const float* conv_b[2] = {(const float*)d_in[9],  (const float*)d_in[17]};
    const float* A_log[2]  = {(const float*)d_in[10], (const float*)d_in[18]};
    const float* Dvec[2]   = {(const float*)d_in[11], (const float*)d_in[19]};
    const float* dt_b[2]   = {(const float*)d_in[12], (const float*)d_in[20]};
    const float* out_w[2]  = {(const float*)d_in[13], (const float*)d_in[21]};
    const float* aux_w = (const float*)d_in[22];
    const float* aux_b = (const float*)d_in[23];
    const float* k1_lbw = (const float*)d_in[24];
    const float* k1_bw  = (const float*)d_in[25];
    const float* k1_bb  = (const float*)d_in[26];
    const float* k1_sw  = (const float*)d_in[27];
    const float* k2_lbw = (const float*)d_in[28];
    const float* k2_bw  = (const float*)d_in[29];
    const float* k2_bb  = (const float*)d_in[30];
    const float* k2_sw  = (const float*)d_in[31];
    const float* sh_w = (const float*)d_in[32];
    const float* sh_b = (const float*)d_in[33];
    const float* hw   = (const float*)d_in[34];
    const float* hbias= (const float*)d_in[35];
    float* ws = (float*)d_ws;
    float* out = (float*)d_out;

    // workspace (float units)
    const size_t o_ApreB   = 0;           // bf16 8192x320
    const size_t o_wpreTB  = 1310720;     // bf16 1024x320
    const size_t o_x1B     = 1474560;     // bf16 8192x1024
    const size_t o_wpatchTB= 5668864;     // bf16 1024x8192 (ends 9,863,168)
    const size_t o_uB   = 0;              // bf16 2x1024x1024 (overlay after stage dead)
    const size_t o_zxB  = 1048576;        // bf16 2x1024x4160 -> ends 5,308,416
    const size_t o_ysB  = 5308416;        // bf16 2x1024x2048 -> ends 7,405,568
    const size_t o_hf   = 9863168;        // f32 1024x1024
    const size_t o_hb   = 10911744;       // f32 1024x1024 (contiguous)
    const size_t o_spart= 11960320;       // f32 8x1024x1024 -> ends 20,348,928
    const size_t total_f = 20348928;      // ~81 MB
    const size_t o_f1   = 0;
    const size_t o_bas1 = 24576;
    const size_t o_k1   = 221184;
    const size_t o_bas2 = 237568;
    const size_t o_k2   = 368640;
    const size_t o_f4   = 376832;
    const size_t o_part = 385024;
    if (ws_size < total_f * sizeof(float)) return;

    __hip_bfloat16* ApreB   = (__hip_bfloat16*)(ws + o_ApreB);
    __hip_bfloat16* wpreTB  = (__hip_bfloat16*)(ws + o_wpreTB);
    __hip_bfloat16* x1B     = (__hip_bfloat16*)(ws + o_x1B);
    __hip_bfloat16* wpatchTB= (__hip_bfloat16*)(ws + o_wpatchTB);
    __hip_bfloat16* uB      = (__hip_bfloat16*)(ws + o_uB);
    __hip_bfloat16* zxB     = (__hip_bfloat16*)(ws + o_zxB);
    __hip_bfloat16* ysB     = (__hip_bfloat16*)(ws + o_ysB);
    float* hf = ws + o_hf;
    float* hb = ws + o_hb;

    // prep: pre/patch weight transposes + im2col (in_w/out_w now consumed fp32-direct)
    k_prep<<<(PREP_TOT + 255) / 256, 256, 0, stream>>>(
        pre_w, patch_w, x_prefix, wpreTB, wpatchTB, ApreB);
    // pre-conv GEMM (silu) -> x1B
    k_gemm_mfma<128,128,0><<<dim3(8, 64, 1), 512, 0, stream>>>(
        (const ushort*)ApreB, (const ushort*)wpreTB, nullptr, nullptr, pre_b, nullptr, x1B,
        320, 320, 320, 1024, 1024, 1, 1, 1024, 0, 0);
    // patch GEMM split-K=8 -> partials -> finalize + first rmsnorm
    k_gemm_mfma<128,128,0><<<dim3(8, 8, 8), 512, 0, stream>>>(
        (const ushort*)x1B, (const ushort*)wpatchTB, nullptr, nullptr, nullptr, ws + o_spart, nullptr,
        1024, 8192, 8192, 1024, 1024, 2, 8, 1024, 0, (long)1024 * 1024);
    k_patch_fin_rms<<<1024, 256, 0, stream>>>(ws + o_spart, patch_b, norm_w[0], norm_w[1], hf, hb, uB);

    // Mamba stacks (both dirs batched), weights consumed fp32-direct (BF32=1)
    for (int i = 0; i < NL_; ++i) {
        k_gemm_mfma<128,128,1><<<dim3(33, 8, 2), 512, 0, stream>>>(
            (const ushort*)uB, nullptr,
            in_w[0] + (size_t)i * DIN_ * DM_, in_w[1] + (size_t)i * DIN_ * DM_,
            nullptr, nullptr, zxB,
            1024, 1024, 1024, DIN_, DIN_, 0, 1, DIN_, (long)1024 * 1024, (long)1024 * DIN_);
        k_scan<<<512, 256, 0, stream>>>(zxB,
            conv_w[0] + (size_t)i * CONVD_ * 4, conv_w[1] + (size_t)i * CONVD_ * 4,
            conv_b[0] + (size_t)i * CONVD_, conv_b[1] + (size_t)i * CONVD_,
            dt_b[0] + i * NH_, dt_b[1] + i * NH_, A_log[0] + i * NH_, A_log[1] + i * NH_,
            Dvec[0] + i * NH_, Dvec[1] + i * NH_, ysB);
        k_gemm_mfma<128,128,1><<<dim3(8, 8, 8), 512, 0, stream>>>(
            (const ushort*)ysB, nullptr,
            out_w[0] + (size_t)i * DM_ * DI_, out_w[1] + (size_t)i * DM_ * DI_,
            nullptr, ws + o_spart, nullptr,
            512, 2048, 2048, 1024, 1024, 2, 4, 1024, (long)1024 * 2048, (long)1024 * 1024);
        if (i + 1 < NL_) {
            k_oproj_fin_rms<true><<<2048, 256, 0, stream>>>(ws + o_spart,
                norm_w[0] + (size_t)(i + 1) * DM_, norm_w[1] + (size_t)(i + 1) * DM_, hf, uB);
        } else {
            k_oproj_fin_rms<false><<<2048, 256, 0, stream>>>(ws + o_spart, nullptr, nullptr, hf, nullptr);
        }
    }

    // Tail (basis1 fused into meanctx_aux)
    k_meanctx_aux<<<68, 256, 0, stream>>>(hf, hb, y_aux, aux_w, aux_b, k1_lbw, ws + o_f1, ws + o_bas1);
    k_dotk<0><<<dim3(64, 27), 256, 0, stream>>>(k1_sw, ws + o_bas1, 24576, k1_bw, ws + o_f1, 3072,
                                                nullptr, ws + o_part, 24, 27, 2048);
    k_fin1_basis2<<<8, 256, 0, stream>>>(ws + o_part, k1_bb, k2_lbw, ws + o_k1, ws + o_bas2);
    k_dotk<0><<<dim3(32, 18), 256, 0, stream>>>(k2_sw, ws + o_bas2, 16384, k2_bw, ws + o_k1, 2048,
                                                nullptr, ws + o_part, 16, 18, 1024);
    k_dot_fin<18><<<4, 256, 0, stream>>>(ws + o_part, k2_bb, ws + o_k2, 1024);
    k_dotk<1><<<dim3(32, 1), 256, 0, stream>>>(nullptr, nullptr, 0, sh_w, ws + o_k2, 1024,
                                               sh_b, ws + o_f4, 0, 1, 1024);
    k_dotk<2><<<dim3(1024, 1), 256, 0, stream>>>(nullptr, nullptr, 0, hw, ws + o_f4, 1024,
                                                 hbias, out, 0, 1, 32768);
}

// Round 13
// 835.651 us; speedup vs baseline: 1.0200x; 1.0200x over previous
//
#include <hip/hip_runtime.h>
#include <hip/hip_bf16.h>
#include <math.h>

#define B_    8
#define LP_   1024
#define CIN_  64
#define DM_   1024
#define DI_   2048
#define NS_   16
#define PH_   64
#define NH_   32
#define NL_   4
#define GG_   8
#define KH_   2048
#define DIN_  4160
#define NPAD_ 4224
#define CONVD_ 2080
#define L_    128
#define R_    1024
#define OUTL_ 512
#define COUT_ 64

typedef __bf16 bf16x8 __attribute__((ext_vector_type(8)));
typedef float f32x4 __attribute__((ext_vector_type(4)));
typedef unsigned short ushort;

__device__ __forceinline__ float silu_f(float x) { return x / (1.0f + expf(-x)); }

__device__ __forceinline__ ushort f2bu(float x) {
    union { __hip_bfloat16 h; ushort u; } c; c.h = __float2bfloat16(x); return c.u;
}
__device__ __forceinline__ float bu2f(ushort u) {
    union { ushort u; __hip_bfloat16 h; } c; c.u = u; return __bfloat162float(c.h);
}

__device__ __forceinline__ void gload_lds16(const void* g, void* l) {
    __builtin_amdgcn_global_load_lds((const __attribute__((address_space(1))) unsigned int*)g,
                                     (__attribute__((address_space(3))) unsigned int*)l, 16, 0, 0);
}

// pair-merge reduce: 8 accumulators x 64 lanes -> lane (l&7) holds full sum of acc[l&7]
__device__ __forceinline__ float merge2(float a, float b, int mask, int lane) {
    float x = (lane & mask) ? b : a;
    float y = (lane & mask) ? a : b;
    return x + __shfl_xor(y, mask);
}
__device__ __forceinline__ float reduce8(float* a, int lane) {
    float c0 = merge2(a[0], a[1], 1, lane);
    float c1 = merge2(a[2], a[3], 1, lane);
    float c2 = merge2(a[4], a[5], 1, lane);
    float c3 = merge2(a[6], a[7], 1, lane);
    float d0 = merge2(c0, c1, 2, lane);
    float d1 = merge2(c2, c3, 2, lane);
    float e  = merge2(d0, d1, 4, lane);
    e += __shfl_xor(e, 8);
    e += __shfl_xor(e, 16);
    e += __shfl_xor(e, 32);
    return e;
}

// ---------------- merged conversion + prep (one dispatch) ----------------
#define CVT_IN_T4  1081344   // NPAD_*1024/4
#define CVT_OUT_T4 524288    // 1024*2048/4
#define CVT_PER    1605632
#define CVT_TOT    12845056  // 8*CVT_PER
#define PREP_W1 327680       // DM_*320
#define PREP_W2 8388608      // DM_*8192
#define PREP_W3 2621440      // 8192*320
#define PREP_TOT 11337728
__global__ __launch_bounds__(256) void k_cvt_prep(
    const float* __restrict__ in0, const float* __restrict__ in1,
    const float* __restrict__ o0, const float* __restrict__ o1,
    __hip_bfloat16* __restrict__ wBBa, __hip_bfloat16* __restrict__ wOBa,
    const float* __restrict__ pre_w, const float* __restrict__ patch_w, const float* __restrict__ xp,
    __hip_bfloat16* __restrict__ wpreT, __hip_bfloat16* __restrict__ wpatchT, __hip_bfloat16* __restrict__ Apre)
{
    int gi = blockIdx.x * 256 + threadIdx.x;
    if (gi < CVT_TOT) {
        int ld = gi / CVT_PER;
        int r = gi - ld * CVT_PER;
        int l = ld >> 1, d = ld & 1;
        const float* inw  = (d ? in1 : in0) + (size_t)l * DIN_ * DM_;
        const float* outw = (d ? o1 : o0) + (size_t)l * DM_ * DI_;
        if (r < CVT_IN_T4) {
            int idx = r * 4; int row = idx >> 10;
            __hip_bfloat16* dst = wBBa + (size_t)ld * NPAD_ * 1024 + idx;
            if (row < DIN_) {
                float4 v = *(const float4*)(inw + idx);
                dst[0] = __float2bfloat16(v.x); dst[1] = __float2bfloat16(v.y);
                dst[2] = __float2bfloat16(v.z); dst[3] = __float2bfloat16(v.w);
            } else {
                dst[0] = __float2bfloat16(0.f); dst[1] = __float2bfloat16(0.f);
                dst[2] = __float2bfloat16(0.f); dst[3] = __float2bfloat16(0.f);
            }
        } else {
            int idx = (r - CVT_IN_T4) * 4;
            __hip_bfloat16* dst = wOBa + (size_t)ld * 2048 * 1024 + idx;
            float4 v = *(const float4*)(outw + idx);
            dst[0] = __float2bfloat16(v.x); dst[1] = __float2bfloat16(v.y);
            dst[2] = __float2bfloat16(v.z); dst[3] = __float2bfloat16(v.w);
        }
        return;
    }
    int idx = gi - CVT_TOT;
    if (idx < PREP_W1) {
        int d = idx / 320, kk = idx % 320;
        int kp = kk >> 6, c = kk & 63;
        wpreT[idx] = __float2bfloat16(pre_w[(d * CIN_ + c) * 5 + kp]);
    } else if (idx < PREP_W1 + PREP_W2) {
        int i = idx - PREP_W1;
        int d = i >> 13, kk = i & 8191;
        int kp = kk >> 10, din = kk & 1023;
        wpatchT[i] = __float2bfloat16(patch_w[((size_t)d << 13) + din * 8 + kp]);
    } else if (idx < PREP_TOT) {
        int i = idx - PREP_W1 - PREP_W2;
        int kk = i % 320; int r = i / 320;
        int l = r & 1023, b = r >> 10;
        int kp = kk >> 6, c = kk & 63;
        int lp = l + kp - 2;
        float v = 0.f;
        if (lp >= 0 && lp < LP_) v = xp[((size_t)b * LP_ + lp) * CIN_ + c];
        Apre[i] = __float2bfloat16(v);
    }
}

// ---------------- bf16 MFMA GEMM, 128^2 tile, 8 waves, BK=32, dbuf, granule swizzle,
// ---------------- T1 XCD-aware bijective block swizzle (B-panel L2 locality) ----------------
template<int BM, int BN>
__global__ __launch_bounds__(512) void k_gemm_mfma(
    const ushort* __restrict__ A, const ushort* __restrict__ B,
    const float* __restrict__ bias,
    float* __restrict__ Cf, __hip_bfloat16* __restrict__ Cb,
    int Kc, int ldk, int ldc, int Nstore, int act, int nsplit,
    long sA, long sB, long sC)
{
    constexpr int BK = 32;
    constexpr int WM = 64, WN = 32;           // 2x4 waves cover 128x128
    constexpr int MR = WM / 16, NR = WN / 16; // 4 x 2
    constexpr int ACH = BM * 4, BCH = BN * 4;
    __shared__ ushort sAs[2][BM * BK];
    __shared__ ushort sBs[2][BN * BK];
    int tid = threadIdx.x;
    int lane = tid & 63, w = tid >> 6;        // 8 waves
    int wr = w >> 2, wc = w & 3;
    int z = blockIdx.z;
    int dir = z / nsplit, ks = z - dir * nsplit;
    int kbase = ks * Kc;
    // T1: XCD-chunked bijective remap (m204, r==0 since nwg%8==0 for all our grids).
    int H = blockIdx.y * gridDim.x + blockIdx.x;
    int nwg = gridDim.x * gridDim.y;
    int chunk = nwg >> 3;
    int Lid = (H & 7) * chunk + (H >> 3);
    int bx = Lid / gridDim.y;
    int by = Lid - bx * gridDim.y;
    int m0 = by * BM, n0 = bx * BN;
    const ushort* Az = A + (size_t)dir * sA + kbase;
    const ushort* Bz = B + (size_t)dir * sB + kbase;

    auto STAGE = [&](int buf, int k0) {
        #pragma unroll
        for (int c = tid; c < ACH; c += 512) {
            int row = c >> 2, gp = c & 3;
            int g = gp ^ ((row >> 1) & 3);            // pre-swizzled source granule
            gload_lds16(Az + (size_t)(m0 + row) * ldk + k0 + g * 8, (char*)&sAs[buf][0] + c * 16);
        }
        #pragma unroll
        for (int c = tid; c < BCH; c += 512) {
            int row = c >> 2, gp = c & 3;
            int g = gp ^ ((row >> 1) & 3);
            gload_lds16(Bz + (size_t)(n0 + row) * ldk + k0 + g * 8, (char*)&sBs[buf][0] + c * 16);
        }
    };

    // swizzled fragment granule (elements)
    const int gsw = (((lane >> 4) ^ ((lane >> 1) & 3)) * 8);

    f32x4 acc[MR][NR] = {};
    const int NT = Kc / BK;
    STAGE(0, 0);
    __syncthreads();
    int cur = 0;
    for (int t = 0; t < NT; ++t) {
        if (t + 1 < NT) STAGE(cur ^ 1, (t + 1) * BK);   // in flight during compute
        bf16x8 af[MR], bfr[NR];
        #pragma unroll
        for (int m = 0; m < MR; ++m)
            af[m] = *(const bf16x8*)&sAs[cur][(wr * WM + m * 16 + (lane & 15)) * BK + gsw];
        #pragma unroll
        for (int n = 0; n < NR; ++n)
            bfr[n] = *(const bf16x8*)&sBs[cur][(wc * WN + n * 16 + (lane & 15)) * BK + gsw];
        #pragma unroll
        for (int m = 0; m < MR; ++m)
            #pragma unroll
            for (int n = 0; n < NR; ++n)
                acc[m][n] = __builtin_amdgcn_mfma_f32_16x16x32_bf16(af[m], bfr[n], acc[m][n], 0, 0, 0);
        __syncthreads();    // implicit vmcnt(0): next tile landed, cur fully consumed
        cur ^= 1;
    }
    #pragma unroll
    for (int m = 0; m < MR; ++m) {
        int row = m0 + wr * WM + m * 16 + (lane >> 4) * 4;
        #pragma unroll
        for (int n = 0; n < NR; ++n) {
            int col = n0 + wc * WN + n * 16 + (lane & 15);
            if (col < Nstore) {
                if (act == 2) {
                    float* Cfz = Cf + (size_t)z * sC;
                    #pragma unroll
                    for (int j = 0; j < 4; ++j)
                        Cfz[(size_t)(row + j) * ldc + col] = acc[m][n][j];
                } else {
                    __hip_bfloat16* Cbz = Cb + (size_t)dir * sC;
                    float bv = bias ? bias[col] : 0.f;
                    #pragma unroll
                    for (int j = 0; j < 4; ++j) {
                        float v = acc[m][n][j] + bv;
                        if (act == 1) v = silu_f(v);
                        Cbz[(size_t)(row + j) * ldc + col] = __float2bfloat16(v);
                    }
                }
            }
        }
    }
}

// ---------------- patch finalize + first rmsnorm: one block per hf row ----------------
__global__ __launch_bounds__(256) void k_patch_fin_rms(const float* __restrict__ part, const float* __restrict__ bias,
                                                       const float* __restrict__ w0, const float* __restrict__ w1,
                                                       float* __restrict__ hf, float* __restrict__ hb,
                                                       __hip_bfloat16* __restrict__ uB) {
    int r = blockIdx.x;          // 0..1023
    int t = threadIdx.x;
    int c = t * 4;
    float4 o = *(const float4*)(bias + c);
    #pragma unroll
    for (int s = 0; s < 8; ++s) {
        float4 v = *(const float4*)(part + (size_t)s * 1048576 + ((size_t)r << 10) + c);
        o.x += v.x; o.y += v.y; o.z += v.z; o.w += v.w;
    }
    *(float4*)(hf + ((size_t)r << 10) + c) = o;
    int rb = r ^ 127;
    *(float4*)(hb + ((size_t)rb << 10) + c) = o;
    float ss = o.x * o.x + o.y * o.y + o.z * o.z + o.w * o.w;
    #pragma unroll
    for (int of = 32; of; of >>= 1) ss += __shfl_xor(ss, of);
    __shared__ float sred[4];
    if ((t & 63) == 0) sred[t >> 6] = ss;
    __syncthreads();
    float tot = sred[0] + sred[1] + sred[2] + sred[3];
    float scale = rsqrtf(tot * (1.0f / DM_) + 1e-5f);
    float4 wf = *(const float4*)(w0 + c);
    float4 wb = *(const float4*)(w1 + c);
    __hip_bfloat16* uf = uB + ((size_t)r << 10) + c;
    __hip_bfloat16* ub = uB + ((size_t)(1024 + rb) << 10) + c;
    uf[0] = __float2bfloat16(o.x * scale * wf.x); uf[1] = __float2bfloat16(o.y * scale * wf.y);
    uf[2] = __float2bfloat16(o.z * scale * wf.z); uf[3] = __float2bfloat16(o.w * scale * wf.w);
    ub[0] = __float2bfloat16(o.x * scale * wb.x); ub[1] = __float2bfloat16(o.y * scale * wb.y);
    ub[2] = __float2bfloat16(o.z * scale * wb.z); ub[3] = __float2bfloat16(o.w * scale * wb.w);
}

// ---------------- out-proj finalize (+residual) + next rmsnorm: one block per h row (2048) ----------------
template<bool DO_RMS>
__global__ __launch_bounds__(256) void k_oproj_fin_rms(const float* __restrict__ part,
                                                       const float* __restrict__ w0, const float* __restrict__ w1,
                                                       float* __restrict__ h, __hip_bfloat16* __restrict__ uB) {
    int row = blockIdx.x;        // 0..2047 (dir = row>>10)
    int t = threadIdx.x;
    int c = t * 4;
    const float* p = part + (size_t)(row >> 10) * 4194304 + (size_t)(row & 1023) * 1024 + c;
    float4 o = *(const float4*)(h + ((size_t)row << 10) + c);
    #pragma unroll
    for (int s = 0; s < 4; ++s) {
        float4 v = *(const float4*)(p + (size_t)s * 1048576);
        o.x += v.x; o.y += v.y; o.z += v.z; o.w += v.w;
    }
    *(float4*)(h + ((size_t)row << 10) + c) = o;
    if (DO_RMS) {
        float ss = o.x * o.x + o.y * o.y + o.z * o.z + o.w * o.w;
        #pragma unroll
        for (int of = 32; of; of >>= 1) ss += __shfl_xor(ss, of);
        __shared__ float sred[4];
        if ((t & 63) == 0) sred[t >> 6] = ss;
        __syncthreads();
        float tot = sred[0] + sred[1] + sred[2] + sred[3];
        float scale = rsqrtf(tot * (1.0f / DM_) + 1e-5f);
        const float* w = (row >> 10) ? w1 : w0;
        float4 wv = *(const float4*)(w + c);
        __hip_bfloat16* u = uB + ((size_t)row << 10) + c;
        u[0] = __float2bfloat16(o.x * scale * wv.x); u[1] = __float2bfloat16(o.y * scale * wv.y);
        u[2] = __float2bfloat16(o.z * scale * wv.z); u[3] = __float2bfloat16(o.w * scale * wv.w);
    }
}

// ---------------- SSM scan with fused depthwise conv: one block per (dir,b,h) ----------------
__global__ __launch_bounds__(256) void k_scan(const __hip_bfloat16* __restrict__ zx,
                                              const float* __restrict__ cw0, const float* __restrict__ cw1,
                                              const float* __restrict__ cb0, const float* __restrict__ cb1,
                                              const float* __restrict__ dtb0, const float* __restrict__ dtb1,
                                              const float* __restrict__ al0, const float* __restrict__ al1,
                                              const float* __restrict__ D0, const float* __restrict__ D1,
                                              __hip_bfloat16* __restrict__ ys) {
    __shared__ float xs[L_ * PH_];
    __shared__ float Bsh[L_ * NS_];
    __shared__ float Csh[L_ * NS_];
    __shared__ float dts[L_];
    __shared__ float dAs[L_];
    int bx = blockIdx.x;
    int dir = bx >> 8, b = (bx >> 5) & 7, h = bx & 31;
    const __hip_bfloat16* zxd = zx + (size_t)dir * 1024 * DIN_;
    const float* cw = dir ? cw1 : cw0;
    const float* cb = dir ? cb1 : cb0;
    const float* dt_bias = dir ? dtb1 : dtb0;
    const float* A_log   = dir ? al1 : al0;
    const float* Dh      = dir ? D1 : D0;
    __hip_bfloat16* ysd  = ys + (size_t)dir * 1024 * DI_;
    int t = threadIdx.x;
    for (int i = t; i < 2048; i += 256) {
        int l = i >> 4, p4 = i & 15;
        int cc = h * PH_ + p4 * 4;
        float a0 = cb[cc + 0], a1 = cb[cc + 1], a2 = cb[cc + 2], a3 = cb[cc + 3];
        #pragma unroll
        for (int k = 0; k < 4; ++k) {
            int lp = l - 3 + k;
            if (lp >= 0) {
                ushort4 raw = *(const ushort4*)(zxd + (size_t)(b * L_ + lp) * DIN_ + DI_ + cc);
                a0 += bu2f(raw.x) * cw[(cc + 0) * 4 + k];
                a1 += bu2f(raw.y) * cw[(cc + 1) * 4 + k];
                a2 += bu2f(raw.z) * cw[(cc + 2) * 4 + k];
                a3 += bu2f(raw.w) * cw[(cc + 3) * 4 + k];
            }
        }
        float* xp = &xs[l * PH_ + p4 * 4];
        xp[0] = silu_f(a0); xp[1] = silu_f(a1); xp[2] = silu_f(a2); xp[3] = silu_f(a3);
    }
    for (int i = t; i < 1024; i += 256) {
        int l = i >> 3, q4 = i & 7;
        int cc = DI_ + q4 * 4;
        float a0 = cb[cc + 0], a1 = cb[cc + 1], a2 = cb[cc + 2], a3 = cb[cc + 3];
        #pragma unroll
        for (int k = 0; k < 4; ++k) {
            int lp = l - 3 + k;
            if (lp >= 0) {
                ushort4 raw = *(const ushort4*)(zxd + (size_t)(b * L_ + lp) * DIN_ + DI_ + cc);
                a0 += bu2f(raw.x) * cw[(cc + 0) * 4 + k];
                a1 += bu2f(raw.y) * cw[(cc + 1) * 4 + k];
                a2 += bu2f(raw.z) * cw[(cc + 2) * 4 + k];
                a3 += bu2f(raw.w) * cw[(cc + 3) * 4 + k];
            }
        }
        float r0 = silu_f(a0), r1 = silu_f(a1), r2 = silu_f(a2), r3 = silu_f(a3);
        if (q4 < 4) {
            float* bp = &Bsh[l * NS_ + q4 * 4];
            bp[0] = r0; bp[1] = r1; bp[2] = r2; bp[3] = r3;
        } else {
            float* cp = &Csh[l * NS_ + (q4 - 4) * 4];
            cp[0] = r0; cp[1] = r1; cp[2] = r2; cp[3] = r3;
        }
    }
    if (t < L_) {
        float v = bu2f(*(const ushort*)(zxd + (size_t)(b * L_ + t) * DIN_ + 4128 + h)) + dt_bias[h];
        float sp = v > 20.f ? v : log1pf(expf(v));
        dts[t] = sp;
        dAs[t] = expf(-expf(A_log[h]) * sp);
    }
    __syncthreads();
    int p = t >> 2, n0 = (t & 3) * 4;
    float Dv = Dh[h];
    float s0 = 0.f, s1 = 0.f, s2 = 0.f, s3 = 0.f;
    for (int l = 0; l < L_; ++l) {
        float x = xs[l * 64 + p];
        float dAv = dAs[l];
        float xdt = x * dts[l];
        s0 = s0 * dAv + xdt * Bsh[l * 16 + n0 + 0];
        s1 = s1 * dAv + xdt * Bsh[l * 16 + n0 + 1];
        s2 = s2 * dAv + xdt * Bsh[l * 16 + n0 + 2];
        s3 = s3 * dAv + xdt * Bsh[l * 16 + n0 + 3];
        float cp = s0 * Csh[l * 16 + n0 + 0] + s1 * Csh[l * 16 + n0 + 1]
                 + s2 * Csh[l * 16 + n0 + 2] + s3 * Csh[l * 16 + n0 + 3];
        cp += __shfl_xor(cp, 1);
        cp += __shfl_xor(cp, 2);
        if ((t & 3) == 0) xs[l * 64 + p] = cp + x * Dv;
    }
    __syncthreads();
    for (int i = t; i < L_ * PH_; i += 256) {
        int l = i >> 6, pp = i & 63;
        float z = bu2f(*(const ushort*)(zxd + (size_t)(b * L_ + l) * DIN_ + h * PH_ + pp));
        ysd[((size_t)(b * L_ + l)) * DI_ + h * PH_ + pp] = __float2bfloat16(xs[i] * silu_f(z));
    }
}

// ---------------- tail: meanctx + aux + KAN1 basis, one dispatch ----------------
__device__ __forceinline__ void emit_basis(float v, float lbw, float* __restrict__ bas, size_t base) {
    float bw = expf(lbw) + 1e-6f;
    float inv = 1.0f / (2.0f * bw * bw);
    #pragma unroll
    for (int g = 0; g < GG_; ++g) {
        float gg = -2.0f + g * (4.0f / 7.0f);
        float df = v - gg;
        bas[base + g] = expf(-df * df * inv);
    }
}

__global__ __launch_bounds__(256) void k_meanctx_aux(const float* __restrict__ hf, const float* __restrict__ hb,
                                                     const float* __restrict__ y_aux, const float* __restrict__ aux_w,
                                                     const float* __restrict__ aux_b, const float* __restrict__ k1_lbw,
                                                     float* __restrict__ fused, float* __restrict__ bas1) {
    int bx = blockIdx.x;
    int t = threadIdx.x;
    if (bx < 64) {
        int b = bx >> 3, ch = bx & 7;
        int d4 = t & 31, lg = t >> 5;
        int d = ch * 128 + d4 * 4;
        float4 sf = {0,0,0,0}, sb = {0,0,0,0};
        for (int l = lg; l < L_; l += 8) {
            float4 a = *(const float4*)(hf + ((size_t)b * L_ + l) * DM_ + d);
            float4 c = *(const float4*)(hb + ((size_t)b * L_ + l) * DM_ + d);
            sf.x += a.x; sf.y += a.y; sf.z += a.z; sf.w += a.w;
            sb.x += c.x; sb.y += c.y; sb.z += c.z; sb.w += c.w;
        }
        __shared__ float rf[8][128], rb[8][128];
        *(float4*)&rf[lg][d4 * 4] = sf;
        *(float4*)&rb[lg][d4 * 4] = sb;
        __syncthreads();
        if (t < 128) {
            float s1 = 0.f, s2 = 0.f;
            #pragma unroll
            for (int g = 0; g < 8; ++g) { s1 += rf[g][t]; s2 += rb[g][t]; }
            s1 *= (1.f / L_); s2 *= (1.f / L_);
            int d1 = ch * 128 + t, d2 = DM_ + ch * 128 + t;
            fused[b * 3072 + d1] = s1;
            fused[b * 3072 + d2] = s2;
            emit_basis(s1, k1_lbw[d1], bas1, ((size_t)b * 3072 + d1) * GG_);
            emit_basis(s2, k1_lbw[d2], bas1, ((size_t)b * 3072 + d2) * GG_);
        }
    } else {
        int j = (bx - 64) * 256 + t;
        if (j >= DM_) return;
        for (int b = 0; b < B_; ++b) {
            float acc = aux_b[j];
            for (int a = 0; a < 32; ++a) acc += y_aux[b * 32 + a] * aux_w[j * 32 + a];
            float v = silu_f(acc);
            int d3 = 2 * DM_ + j;
            fused[b * 3072 + d3] = v;
            emit_basis(v, k1_lbw[d3], bas1, ((size_t)b * 3072 + d3) * GG_);
        }
    }
}

// ---------------- LDS-staged batched dot; y-chunks cover spline (ch<nsp) and base (ch>=nsp) ----------------
template<int MODE>
__global__ __launch_bounds__(256) void k_dotk(const float* __restrict__ Wsp, const float* __restrict__ Xsp, int Ksp,
                                              const float* __restrict__ Wb, const float* __restrict__ Xb, int Kb,
                                              const float* __restrict__ bias, float* __restrict__ out,
                                              int nsp, int nch, int Dout) {
    __shared__ float sX[8][1024];
    int ch = blockIdx.y;
    bool sp = (ch < nsp);
    const float* W = sp ? Wsp : Wb;
    const float* X = sp ? Xsp : Xb;
    int K = sp ? Ksp : Kb;
    int k0 = (sp ? ch : ch - nsp) * 1024;
    int tid = threadIdx.x;
    for (int i = tid; i < 2048; i += 256) {
        int b = i >> 8, kk = (i & 255) * 4;
        *(float4*)&sX[b][kk] = *(const float4*)(X + (size_t)b * K + k0 + kk);
    }
    __syncthreads();
    int wv = tid >> 6, lane = tid & 63;
    int rowBase = blockIdx.x * 32 + wv * 8;
    for (int j = 0; j < 8; ++j) {
        int row = rowBase + j;
        const float* wr = W + (size_t)row * K + k0;
        float acc[8] = {};
        #pragma unroll
        for (int it = 0; it < 4; ++it) {
            int k = it * 256 + lane * 4;
            float4 wvv = *(const float4*)(wr + k);
            #pragma unroll
            for (int b = 0; b < 8; ++b) {
                float4 xv = *(const float4*)&sX[b][k];
                acc[b] += wvv.x * xv.x + wvv.y * xv.y + wvv.z * xv.z + wvv.w * xv.w;
            }
        }
        float e = reduce8(acc, lane);
        if (lane < 8) {
            if (MODE == 0) {
                out[((size_t)row * nch + ch) * 8 + lane] = e;
            } else if (MODE == 1) {
                out[(size_t)lane * Dout + row] = silu_f(e + bias[row]);
            } else {
                int c = row >> 9, l = row & 511;
                out[((size_t)lane * OUTL_ + l) * COUT_ + c] = e + bias[row];
            }
        }
    }
}

// ---------------- KAN1 finalize + basis2 fused ----------------
__global__ __launch_bounds__(256) void k_fin1_basis2(const float* __restrict__ partial, const float* __restrict__ bb,
                                                     const float* __restrict__ k2_lbw,
                                                     float* __restrict__ k1, float* __restrict__ bas2) {
    int row = blockIdx.x * 256 + threadIdx.x;   // 0..2047
    if (row >= 2048) return;
    float bbv = bb[row];
    float lb = expf(k2_lbw[row]) + 1e-6f;
    float inv = 1.0f / (2.0f * lb * lb);
    #pragma unroll
    for (int b = 0; b < 8; ++b) {
        float s = bbv;
        #pragma unroll
        for (int c = 0; c < 27; ++c) s += partial[((size_t)row * 27 + c) * 8 + b];
        float v = silu_f(s);
        k1[(size_t)b * 2048 + row] = v;
        #pragma unroll
        for (int g = 0; g < GG_; ++g) {
            float gg = -2.0f + g * (4.0f / 7.0f);
            float df = v - gg;
            bas2[((size_t)b * 2048 + row) * GG_ + g] = expf(-df * df * inv);
        }
    }
}

template<int NCH>
__global__ __launch_bounds__(256) void k_dot_fin(const float* __restrict__ partial, const float* __restrict__ base_b,
                                                 float* __restrict__ out, int Dout) {
    int row = blockIdx.x * 256 + threadIdx.x;
    if (row >= Dout) return;
    float bb = base_b[row];
    #pragma unroll
    for (int b = 0; b < 8; ++b) {
        float s = bb;
        #pragma unroll
        for (int c = 0; c < NCH; ++c) s += partial[((size_t)row * NCH + c) * 8 + b];
        out[(size_t)b * Dout + row] = silu_f(s);
    }
}

// ---------------- launch ----------------
extern "C" void kernel_launch(void* const* d_in, const int* in_sizes, int n_in,
                              void* d_out, int out_size, void* d_ws, size_t ws_size,
                              hipStream_t stream) {
    const float* x_prefix = (const float*)d_in[0];
    const float* y_aux    = (const float*)d_in[1];
    const float* pre_w    = (const float*)d_in[2];
    const float* pre_b    = (const float*)d_in[3];
    const float* patch_w  = (const float*)d_in[4];
    const float* patch_b  = (const float*)d_in[5];
    const float* norm_w[2] = {(const float*)d_in[6],  (const float*)d_in[14]};
    const float* in_w[2]   = {(const float*)d_in[7],  (const float*)d_in[15]};
    const float* conv_w[2] = {(const float*)d_in[8],  (const float*)d_in[16]};
    const float* conv_b[2] = {(const float*)d_in[9],  (const float*)d_in[17]};
    const float* A_log[2]  = {(const float*)d_in[10], (const float*)d_in[18]};
    const float* Dvec[2]   = {(const float*)d_in[11], (const float*)d_in[19]};
    const float* dt_b[2]   = {(const float*)d_in[12], (const float*)d_in[20]};
    const float* out_w[2]  = {(const float*)d_in[13], (const float*)d_in[21]};
    const float* aux_w = (const float*)d_in[22];
    const float* aux_b = (const float*)d_in[23];
    const float* k1_lbw = (const float*)d_in[24];
    const float* k1_bw  = (const float*)d_in[25];
    const float* k1_bb  = (const float*)d_in[26];
    const float* k1_sw  = (const float*)d_in[27];
    const float* k2_lbw = (const float*)d_in[28];
    const float* k2_bw  = (const float*)d_in[29];
    const float* k2_bb  = (const float*)d_in[30];
    const float* k2_sw  = (const float*)d_in[31];
    const float* sh_w = (const float*)d_in[32];
    const float* sh_b = (const float*)d_in[33];
    const float* hw   = (const float*)d_in[34];
    const float* hbias= (const float*)d_in[35];
    float* ws = (float*)d_ws;
    float* out = (float*)d_out;

    // workspace (float units)
    const size_t o_ApreB   = 0;
    const size_t o_wpreTB  = 1310720;
    const size_t o_x1B     = 1474560;
    const size_t o_wpatchTB= 5668864;
    const size_t o_uB   = 0;              // bf16 2x1024x1024
    const size_t o_zxB  = 1048576;        // bf16 2x1024x4160 -> ends 5,308,416
    const size_t o_ysB  = 5308416;        // bf16 2x1024x2048 -> ends 7,405,568
    const size_t o_hf   = 9863168;        // f32 1024x1024
    const size_t o_hb   = 10911744;       // f32 1024x1024 (contiguous)
    const size_t o_wBBa = 11960320;       // bf16 4x2x4224x1024 -> ends 29,261,824
    const size_t o_wOBa = 29261824;       // bf16 4x2x2048x1024 -> ends 37,650,432
    const size_t o_spart= 37650432;       // f32 8x1024x1024 -> ends 46,039,040
    const size_t total_f = 46039040;      // ~184 MB
    const size_t o_f1   = 0;
    const size_t o_bas1 = 24576;
    const size_t o_k1   = 221184;
    const size_t o_bas2 = 237568;
    const size_t o_k2   = 368640;
    const size_t o_f4   = 376832;
    const size_t o_part = 385024;
    if (ws_size < total_f * sizeof(float)) return;

    __hip_bfloat16* ApreB   = (__hip_bfloat16*)(ws + o_ApreB);
    __hip_bfloat16* wpreTB  = (__hip_bfloat16*)(ws + o_wpreTB);
    __hip_bfloat16* x1B     = (__hip_bfloat16*)(ws + o_x1B);
    __hip_bfloat16* wpatchTB= (__hip_bfloat16*)(ws + o_wpatchTB);
    __hip_bfloat16* uB      = (__hip_bfloat16*)(ws + o_uB);
    __hip_bfloat16* zxB     = (__hip_bfloat16*)(ws + o_zxB);
    __hip_bfloat16* ysB     = (__hip_bfloat16*)(ws + o_ysB);
    __hip_bfloat16* wBBa    = (__hip_bfloat16*)(ws + o_wBBa);
    __hip_bfloat16* wOBa    = (__hip_bfloat16*)(ws + o_wOBa);
    float* hf = ws + o_hf;
    float* hb = ws + o_hb;

    // merged: all-layer weight conversion + pre/patch prep (one dispatch)
    k_cvt_prep<<<(CVT_TOT + PREP_TOT + 255) / 256, 256, 0, stream>>>(
        in_w[0], in_w[1], out_w[0], out_w[1], wBBa, wOBa,
        pre_w, patch_w, x_prefix, wpreTB, wpatchTB, ApreB);
    // pre-conv GEMM (silu) -> x1B
    k_gemm_mfma<128,128><<<dim3(8, 64, 1), 512, 0, stream>>>(
        (const ushort*)ApreB, (const ushort*)wpreTB, pre_b, nullptr, x1B,
        320, 320, 1024, 1024, 1, 1, 0, 0, 0);
    // patch GEMM split-K=8 -> partials -> finalize + first rmsnorm
    k_gemm_mfma<128,128><<<dim3(8, 8, 8), 512, 0, stream>>>(
        (const ushort*)x1B, (const ushort*)wpatchTB, nullptr, ws + o_spart, nullptr,
        1024, 8192, 1024, 1024, 2, 8, 0, 0, (long)1024 * 1024);
    k_patch_fin_rms<<<1024, 256, 0, stream>>>(ws + o_spart, patch_b, norm_w[0], norm_w[1], hf, hb, uB);

    // Mamba stacks (both dirs batched)
    for (int i = 0; i < NL_; ++i) {
        k_gemm_mfma<128,128><<<dim3(33, 8, 2), 512, 0, stream>>>(
            (const ushort*)uB, (const ushort*)(wBBa + (size_t)i * 2 * NPAD_ * 1024), nullptr, nullptr, zxB,
            1024, 1024, DIN_, DIN_, 0, 1, (long)1024 * 1024, (long)NPAD_ * 1024, (long)1024 * DIN_);
        k_scan<<<512, 256, 0, stream>>>(zxB,
            conv_w[0] + (size_t)i * CONVD_ * 4, conv_w[1] + (size_t)i * CONVD_ * 4,
            conv_b[0] + (size_t)i * CONVD_, conv_b[1] + (size_t)i * CONVD_,
            dt_b[0] + i * NH_, dt_b[1] + i * NH_, A_log[0] + i * NH_, A_log[1] + i * NH_,
            Dvec[0] + i * NH_, Dvec[1] + i * NH_, ysB);
        k_gemm_mfma<128,128><<<dim3(8, 8, 8), 512, 0, stream>>>(
            (const ushort*)ysB, (const ushort*)(wOBa + (size_t)i * 2 * 2048 * 1024), nullptr, ws + o_spart, nullptr,
            512, 2048, 1024, 1024, 2, 4, (long)1024 * 2048, (long)2048 * 1024, (long)1024 * 1024);
        if (i + 1 < NL_) {
            k_oproj_fin_rms<true><<<2048, 256, 0, stream>>>(ws + o_spart,
                norm_w[0] + (size_t)(i + 1) * DM_, norm_w[1] + (size_t)(i + 1) * DM_, hf, uB);
        } else {
            k_oproj_fin_rms<false><<<2048, 256, 0, stream>>>(ws + o_spart, nullptr, nullptr, hf, nullptr);
        }
    }

    // Tail (basis1 fused into meanctx_aux)
    k_meanctx_aux<<<68, 256, 0, stream>>>(hf, hb, y_aux, aux_w, aux_b, k1_lbw, ws + o_f1, ws + o_bas1);
    k_dotk<0><<<dim3(64, 27), 256, 0, stream>>>(k1_sw, ws + o_bas1, 24576, k1_bw, ws + o_f1, 3072,
                                                nullptr, ws + o_part, 24, 27, 2048);
    k_fin1_basis2<<<8, 256, 0, stream>>>(ws + o_part, k1_bb, k2_lbw, ws + o_k1, ws + o_bas2);
    k_dotk<0><<<dim3(32, 18), 256, 0, stream>>>(k2_sw, ws + o_bas2, 16384, k2_bw, ws + o_k1, 2048,
                                                nullptr, ws + o_part, 16, 18, 1024);
    k_dot_fin<18><<<4, 256, 0, stream>>>(ws + o_part, k2_bb, ws + o_k2, 1024);
    k_dotk<1><<<dim3(32, 1), 256, 0, stream>>>(nullptr, nullptr, 0, sh_w, ws + o_k2, 1024,
                                               sh_b, ws + o_f4, 0, 1, 1024);
    k_dotk<2><<<dim3(1024, 1), 256, 0, stream>>>(nullptr, nullptr, 0, hw, ws + o_f4, 1024,
                                                 hbias, out, 0, 1, 32768);
}